// Round 2
// baseline (263.156 us; speedup 1.0000x reference)
//
#include <hip/hip_runtime.h>
#include <hip/hip_bf16.h>

#define AMINOS 1024
#define ATOMS  8192
#define DIM    128

typedef __attribute__((ext_vector_type(8))) short  short8;   // 8 bf16 (4 VGPRs)
typedef __attribute__((ext_vector_type(4))) float  f32x4;

// RNE float -> bf16 (finite inputs only)
__device__ __forceinline__ unsigned short f2bf(float f) {
    unsigned int u; __builtin_memcpy(&u, &f, 4);
    unsigned int r = (u + 0x7fffu + ((u >> 16) & 1u)) >> 16;
    return (unsigned short)r;
}
__device__ __forceinline__ float bf2f(unsigned short us) {
    unsigned int x = ((unsigned int)us) << 16;
    float f; __builtin_memcpy(&f, &x, 4);
    return f;
}

// 16-byte-slot index with XOR swizzle inside a [rows][16-slot] LDS tile
__device__ __forceinline__ int swz(int row, int ch) { return row * 16 + (ch ^ (row & 7)); }

// ---------------- K0: convert the three 128x128 weights to bf16 ----------------
__global__ __launch_bounds__(256) void k_convert(const float* __restrict__ wemb,
                                                 const float* __restrict__ win,
                                                 const float* __restrict__ wout,
                                                 unsigned short* __restrict__ dst) {
    int i = blockIdx.x * 256 + threadIdx.x;          // 0 .. 49151
    const float* src = (i < 16384) ? wemb : ((i < 32768) ? win : wout);
    dst[i] = f2bf(src[i & 16383]);
}

// ---------------- K1: mod[a][f] = sum_e emb[a][e]*W_emb[f][e] + b_emb[f] (f32 out)
__global__ __launch_bounds__(256) void k_mod(const float* __restrict__ emb,
                                             const unsigned short* __restrict__ wembB,
                                             const float* __restrict__ bemb,
                                             float* __restrict__ mod) {
    __shared__ short Al[64 * 128];
    __shared__ short Bl[128 * 128];
    const int tid = threadIdx.x;
    const int a0 = blockIdx.x * 64;

    // A tile: 64 rows (atoms) x 128 (e), bf16, swizzled
    #pragma unroll
    for (int t = 0; t < 4; ++t) {
        int task = tid + t * 256;                    // 1024 tasks
        int row = task >> 4, ch = task & 15;
        const f32x4* p = (const f32x4*)(emb + (a0 + row) * 128 + ch * 8);
        f32x4 lo = p[0], hi = p[1];
        short8 v;
        v[0]=f2bf(lo[0]); v[1]=f2bf(lo[1]); v[2]=f2bf(lo[2]); v[3]=f2bf(lo[3]);
        v[4]=f2bf(hi[0]); v[5]=f2bf(hi[1]); v[6]=f2bf(hi[2]); v[7]=f2bf(hi[3]);
        *(short8*)&Al[swz(row, ch) * 8] = v;
    }
    // B tile: W_emb [f][e] row-major bf16, swizzled
    #pragma unroll
    for (int t = 0; t < 8; ++t) {
        int cc = tid + t * 256;                      // 2048 chunks
        int rr = cc >> 4, ch = cc & 15;
        short8 v = *(const short8*)(wembB + cc * 8);
        *(short8*)&Bl[swz(rr, ch) * 8] = v;
    }
    __syncthreads();

    const int lane = tid & 63, w = tid >> 6;
    const int col = lane & 15, kg = lane >> 4;
    const int rt = w;                                // wave -> row tile

    short8 af[4];
    #pragma unroll
    for (int ks = 0; ks < 4; ++ks) {
        int r = rt * 16 + col;
        af[ks] = *(const short8*)&Al[swz(r, ks * 4 + kg) * 8];
    }
    f32x4 acc[8];
    #pragma unroll
    for (int ct = 0; ct < 8; ++ct) { acc[ct][0]=0.f; acc[ct][1]=0.f; acc[ct][2]=0.f; acc[ct][3]=0.f; }

    #pragma unroll
    for (int ct = 0; ct < 8; ++ct) {
        int r = ct * 16 + col;
        #pragma unroll
        for (int ks = 0; ks < 4; ++ks) {
            short8 bf = *(const short8*)&Bl[swz(r, ks * 4 + kg) * 8];
            acc[ct] = __builtin_amdgcn_mfma_f32_16x16x32_bf16(af[ks], bf, acc[ct], 0, 0, 0);
        }
    }
    #pragma unroll
    for (int ct = 0; ct < 8; ++ct) {
        int f = ct * 16 + col;
        float bb = bemb[f];
        #pragma unroll
        for (int reg = 0; reg < 4; ++reg) {
            int r = rt * 16 + kg * 4 + reg;
            mod[(a0 + r) * 128 + f] = acc[ct][reg] + bb;
        }
    }
}

// ---------------- K2: h[pair][v][e] = sum_c x[pair][c][v] * W_in[e][c]  (bf16 out)
__global__ __launch_bounds__(256) void k_h(const float* __restrict__ x,
                                           const unsigned short* __restrict__ winB,
                                           unsigned short* __restrict__ h) {
    __shared__ short Al[48 * 128];
    __shared__ short Bl[128 * 128];
    const int tid = threadIdx.x;
    const int g0 = blockIdx.x * 16;                  // first (b,m) pair

    // A tile: one task per (pair, c-chunk); 24 consecutive floats = 8 c x 3 v
    {
        int p = tid >> 4, ch = tid & 15;
        const f32x4* q = (const f32x4*)(x + (g0 + p) * 384 + ch * 24);
        f32x4 q0 = q[0], q1 = q[1], q2 = q[2], q3 = q[3], q4 = q[4], q5 = q[5];
        float e[24];
        *(f32x4*)&e[0]  = q0; *(f32x4*)&e[4]  = q1; *(f32x4*)&e[8]  = q2;
        *(f32x4*)&e[12] = q3; *(f32x4*)&e[16] = q4; *(f32x4*)&e[20] = q5;
        #pragma unroll
        for (int v = 0; v < 3; ++v) {
            short8 vv;
            #pragma unroll
            for (int i = 0; i < 8; ++i) vv[i] = (short)f2bf(e[v + 3 * i]);
            *(short8*)&Al[swz(p * 3 + v, ch) * 8] = vv;
        }
    }
    #pragma unroll
    for (int t = 0; t < 8; ++t) {
        int cc = tid + t * 256;
        int rr = cc >> 4, ch = cc & 15;
        short8 v = *(const short8*)(winB + cc * 8);
        *(short8*)&Bl[swz(rr, ch) * 8] = v;
    }
    __syncthreads();

    const int lane = tid & 63, w = tid >> 6;
    const int col = lane & 15, kg = lane >> 4;

    short8 af[3][4];
    #pragma unroll
    for (int rt = 0; rt < 3; ++rt) {
        int r = rt * 16 + col;
        #pragma unroll
        for (int ks = 0; ks < 4; ++ks) af[rt][ks] = *(const short8*)&Al[swz(r, ks * 4 + kg) * 8];
    }
    f32x4 acc[3][2];
    #pragma unroll
    for (int rt = 0; rt < 3; ++rt)
        #pragma unroll
        for (int c2 = 0; c2 < 2; ++c2) { acc[rt][c2][0]=0.f; acc[rt][c2][1]=0.f; acc[rt][c2][2]=0.f; acc[rt][c2][3]=0.f; }

    #pragma unroll
    for (int c2 = 0; c2 < 2; ++c2) {
        int ct = w * 2 + c2;
        int r = ct * 16 + col;
        #pragma unroll
        for (int ks = 0; ks < 4; ++ks) {
            short8 bf = *(const short8*)&Bl[swz(r, ks * 4 + kg) * 8];
            #pragma unroll
            for (int rt = 0; rt < 3; ++rt)
                acc[rt][c2] = __builtin_amdgcn_mfma_f32_16x16x32_bf16(af[rt][ks], bf, acc[rt][c2], 0, 0, 0);
        }
    }
    #pragma unroll
    for (int rt = 0; rt < 3; ++rt) {
        #pragma unroll
        for (int c2 = 0; c2 < 2; ++c2) {
            int e = (w * 2 + c2) * 16 + col;
            #pragma unroll
            for (int reg = 0; reg < 4; ++reg) {
                int R = rt * 16 + kg * 4 + reg;
                int p = R / 3, v = R - 3 * p;
                h[((g0 + p) * 3 + v) * 128 + e] = f2bf(acc[rt][c2][reg]);
            }
        }
    }
}

// ---------------- K3: out[b,a,d,v] = sum_e W_out[d][e] * mod[a][e] * h[b,idx[a],v,e]
__global__ __launch_bounds__(256) void k_out(const unsigned short* __restrict__ h,
                                             const float* __restrict__ mod,
                                             const int* __restrict__ idx,
                                             const unsigned short* __restrict__ woutB,
                                             float* __restrict__ out) {
    __shared__ short Al[48 * 128];
    __shared__ short Bl[128 * 128];
    const int tid = threadIdx.x;
    const int b = blockIdx.x & 15;                   // batch minor: 16 blocks share mod rows
    const int a0 = (blockIdx.x >> 4) * 16;

    #pragma unroll
    for (int t = 0; t < 3; ++t) {
        int task = tid + t * 256;                    // 768 tasks
        int row = task >> 4, ch = task & 15;
        int al = row / 3, v = row - 3 * al;
        int a = a0 + al;
        int ia = idx[a];
        short8 hv = *(const short8*)(h + ((b * AMINOS + ia) * 3 + v) * 128 + ch * 8);
        const f32x4* mp = (const f32x4*)(mod + a * 128 + ch * 8);
        f32x4 m0 = mp[0], m1 = mp[1];
        short8 vv;
        vv[0]=(short)f2bf(bf2f((unsigned short)hv[0]) * m0[0]);
        vv[1]=(short)f2bf(bf2f((unsigned short)hv[1]) * m0[1]);
        vv[2]=(short)f2bf(bf2f((unsigned short)hv[2]) * m0[2]);
        vv[3]=(short)f2bf(bf2f((unsigned short)hv[3]) * m0[3]);
        vv[4]=(short)f2bf(bf2f((unsigned short)hv[4]) * m1[0]);
        vv[5]=(short)f2bf(bf2f((unsigned short)hv[5]) * m1[1]);
        vv[6]=(short)f2bf(bf2f((unsigned short)hv[6]) * m1[2]);
        vv[7]=(short)f2bf(bf2f((unsigned short)hv[7]) * m1[3]);
        *(short8*)&Al[swz(row, ch) * 8] = vv;
    }
    #pragma unroll
    for (int t = 0; t < 8; ++t) {
        int cc = tid + t * 256;
        int rr = cc >> 4, ch = cc & 15;
        short8 v = *(const short8*)(woutB + cc * 8);
        *(short8*)&Bl[swz(rr, ch) * 8] = v;
    }
    __syncthreads();

    const int lane = tid & 63, w = tid >> 6;
    const int col = lane & 15, kg = lane >> 4;

    short8 af[3][4];
    #pragma unroll
    for (int rt = 0; rt < 3; ++rt) {
        int r = rt * 16 + col;
        #pragma unroll
        for (int ks = 0; ks < 4; ++ks) af[rt][ks] = *(const short8*)&Al[swz(r, ks * 4 + kg) * 8];
    }
    f32x4 acc[3][2];
    #pragma unroll
    for (int rt = 0; rt < 3; ++rt)
        #pragma unroll
        for (int c2 = 0; c2 < 2; ++c2) { acc[rt][c2][0]=0.f; acc[rt][c2][1]=0.f; acc[rt][c2][2]=0.f; acc[rt][c2][3]=0.f; }

    #pragma unroll
    for (int c2 = 0; c2 < 2; ++c2) {
        int ct = w * 2 + c2;
        int r = ct * 16 + col;
        #pragma unroll
        for (int ks = 0; ks < 4; ++ks) {
            short8 bf = *(const short8*)&Bl[swz(r, ks * 4 + kg) * 8];
            #pragma unroll
            for (int rt = 0; rt < 3; ++rt)
                acc[rt][c2] = __builtin_amdgcn_mfma_f32_16x16x32_bf16(af[rt][ks], bf, acc[rt][c2], 0, 0, 0);
        }
    }
    #pragma unroll
    for (int rt = 0; rt < 3; ++rt) {
        #pragma unroll
        for (int c2 = 0; c2 < 2; ++c2) {
            int d = (w * 2 + c2) * 16 + col;
            #pragma unroll
            for (int reg = 0; reg < 4; ++reg) {
                int R = rt * 16 + kg * 4 + reg;
                int al = R / 3, v = R - 3 * al;
                int a = a0 + al;
                out[((b * ATOMS + a) * 128 + d) * 3 + v] = acc[rt][c2][reg];
            }
        }
    }
}

extern "C" void kernel_launch(void* const* d_in, const int* in_sizes, int n_in,
                              void* d_out, int out_size, void* d_ws, size_t ws_size,
                              hipStream_t stream) {
    const float* x    = (const float*)d_in[0];
    const float* emb  = (const float*)d_in[1];
    const int*   idx  = (const int*)d_in[2];
    const float* wemb = (const float*)d_in[3];
    const float* bemb = (const float*)d_in[4];
    const float* win  = (const float*)d_in[5];
    const float* wout = (const float*)d_in[6];
    float* out = (float*)d_out;

    char* ws = (char*)d_ws;
    float*          mod = (float*)ws;                              // 8192*128 f32   = 4 MiB
    unsigned short* h   = (unsigned short*)(ws + (4u << 20));      // 16*1024*3*128 bf16 = 12 MiB
    unsigned short* wB  = (unsigned short*)(ws + 16777216u);       // 3 x 16384 bf16

    k_convert<<<192, 256, 0, stream>>>(wemb, win, wout, wB);
    k_mod    <<<128, 256, 0, stream>>>(emb, wB, bemb, mod);
    k_h      <<<1024, 256, 0, stream>>>(x, wB + 16384, h);
    k_out    <<<8192, 256, 0, stream>>>(h, mod, idx, wB + 32768, out);
}

// Round 3
// 245.419 us; speedup vs baseline: 1.0723x; 1.0723x over previous
//
#include <hip/hip_runtime.h>
#include <hip/hip_bf16.h>

#define AMINOS 1024
#define ATOMS  8192

typedef __attribute__((ext_vector_type(8))) short  short8;   // 8 bf16 (4 VGPRs)
typedef __attribute__((ext_vector_type(4))) float  f32x4;

// RNE float -> bf16 (finite inputs only)
__device__ __forceinline__ unsigned short f2bf(float f) {
    unsigned int u; __builtin_memcpy(&u, &f, 4);
    unsigned int r = (u + 0x7fffu + ((u >> 16) & 1u)) >> 16;
    return (unsigned short)r;
}
__device__ __forceinline__ float bf2f(unsigned short us) {
    unsigned int x = ((unsigned int)us) << 16;
    float f; __builtin_memcpy(&f, &x, 4);
    return f;
}

// 16-byte-slot index with XOR swizzle inside a [rows][16-slot] LDS tile
__device__ __forceinline__ int swz(int row, int ch) { return row * 16 + (ch ^ (row & 7)); }

// ---------------- K0: convert the three 128x128 weights to bf16 ----------------
__global__ __launch_bounds__(256) void k_convert(const float* __restrict__ wemb,
                                                 const float* __restrict__ win,
                                                 const float* __restrict__ wout,
                                                 unsigned short* __restrict__ dst) {
    int i = blockIdx.x * 256 + threadIdx.x;          // 0 .. 49151
    const float* src = (i < 16384) ? wemb : ((i < 32768) ? win : wout);
    dst[i] = f2bf(src[i & 16383]);
}

// ---------------- K1: mod[a][f] = sum_e emb[a][e]*W_emb[f][e] + b_emb[f] (f32 out)
__global__ __launch_bounds__(256) void k_mod(const float* __restrict__ emb,
                                             const unsigned short* __restrict__ wembB,
                                             const float* __restrict__ bemb,
                                             float* __restrict__ mod) {
    __shared__ short Al[64 * 128];
    __shared__ short Bl[128 * 128];
    const int tid = threadIdx.x;
    const int a0 = blockIdx.x * 64;

    #pragma unroll
    for (int t = 0; t < 4; ++t) {
        int task = tid + t * 256;                    // 1024 tasks
        int row = task >> 4, ch = task & 15;
        const f32x4* p = (const f32x4*)(emb + (a0 + row) * 128 + ch * 8);
        f32x4 lo = p[0], hi = p[1];
        short8 v;
        v[0]=f2bf(lo[0]); v[1]=f2bf(lo[1]); v[2]=f2bf(lo[2]); v[3]=f2bf(lo[3]);
        v[4]=f2bf(hi[0]); v[5]=f2bf(hi[1]); v[6]=f2bf(hi[2]); v[7]=f2bf(hi[3]);
        *(short8*)&Al[swz(row, ch) * 8] = v;
    }
    #pragma unroll
    for (int t = 0; t < 8; ++t) {
        int cc = tid + t * 256;                      // 2048 chunks
        int rr = cc >> 4, ch = cc & 15;
        short8 v = *(const short8*)(wembB + cc * 8);
        *(short8*)&Bl[swz(rr, ch) * 8] = v;
    }
    __syncthreads();

    const int lane = tid & 63, w = tid >> 6;
    const int col = lane & 15, kg = lane >> 4;
    const int rt = w;

    short8 af[4];
    #pragma unroll
    for (int ks = 0; ks < 4; ++ks) af[ks] = *(const short8*)&Al[swz(rt * 16 + col, ks * 4 + kg) * 8];

    f32x4 acc[8];
    #pragma unroll
    for (int ct = 0; ct < 8; ++ct) { acc[ct][0]=0.f; acc[ct][1]=0.f; acc[ct][2]=0.f; acc[ct][3]=0.f; }

    #pragma unroll
    for (int ct = 0; ct < 8; ++ct) {
        int r = ct * 16 + col;
        #pragma unroll
        for (int ks = 0; ks < 4; ++ks) {
            short8 bf = *(const short8*)&Bl[swz(r, ks * 4 + kg) * 8];
            acc[ct] = __builtin_amdgcn_mfma_f32_16x16x32_bf16(af[ks], bf, acc[ct], 0, 0, 0);
        }
    }
    #pragma unroll
    for (int ct = 0; ct < 8; ++ct) {
        int f = ct * 16 + col;
        float bb = bemb[f];
        #pragma unroll
        for (int reg = 0; reg < 4; ++reg) {
            int r = rt * 16 + kg * 4 + reg;
            mod[(a0 + r) * 128 + f] = acc[ct][reg] + bb;
        }
    }
}

// ---------------- K2: h[g][v][e] = sum_c x[g][c][v] * W_in[e][c]  (bf16 out)
// 256 blocks x 4 sub-tiles of 16 (b,m) pairs. W_in staged once, frags in regs.
__global__ __launch_bounds__(256) void k_h(const float* __restrict__ x,
                                           const unsigned short* __restrict__ winB,
                                           unsigned short* __restrict__ h) {
    __shared__ short Al[48 * 128];
    __shared__ short Bl[128 * 128];
    unsigned short* Hs = (unsigned short*)Bl;        // epilogue staging aliases Bl (12 KB <= 32 KB)
    const int tid = threadIdx.x;

    #pragma unroll
    for (int t = 0; t < 8; ++t) {
        int cc = tid + t * 256;
        int rr = cc >> 4, ch = cc & 15;
        short8 v = *(const short8*)(winB + cc * 8);
        *(short8*)&Bl[swz(rr, ch) * 8] = v;
    }
    __syncthreads();

    const int lane = tid & 63, w = tid >> 6;
    const int col = lane & 15, kg = lane >> 4;

    short8 bfr[2][4];                                // hoisted W_in fragments
    #pragma unroll
    for (int c2 = 0; c2 < 2; ++c2) {
        int r = (w * 2 + c2) * 16 + col;
        #pragma unroll
        for (int ks = 0; ks < 4; ++ks) bfr[c2][ks] = *(const short8*)&Bl[swz(r, ks * 4 + kg) * 8];
    }

    for (int it = 0; it < 4; ++it) {
        const int g0 = blockIdx.x * 64 + it * 16;
        // stage A: lane owns (pair, c-chunk): 24 consecutive floats = 8 c x 3 v
        {
            int p = tid >> 4, ch = tid & 15;
            const f32x4* q = (const f32x4*)(x + (size_t)(g0 + p) * 384 + ch * 24);
            f32x4 q0 = q[0], q1 = q[1], q2 = q[2], q3 = q[3], q4 = q[4], q5 = q[5];
            float e[24];
            *(f32x4*)&e[0]  = q0; *(f32x4*)&e[4]  = q1; *(f32x4*)&e[8]  = q2;
            *(f32x4*)&e[12] = q3; *(f32x4*)&e[16] = q4; *(f32x4*)&e[20] = q5;
            #pragma unroll
            for (int v = 0; v < 3; ++v) {
                short8 vv;
                #pragma unroll
                for (int i = 0; i < 8; ++i) vv[i] = (short)f2bf(e[v + 3 * i]);
                *(short8*)&Al[swz(p * 3 + v, ch) * 8] = vv;
            }
        }
        __syncthreads();                             // S1

        f32x4 acc[3][2];
        #pragma unroll
        for (int rt = 0; rt < 3; ++rt)
            #pragma unroll
            for (int c2 = 0; c2 < 2; ++c2) { acc[rt][c2][0]=0.f; acc[rt][c2][1]=0.f; acc[rt][c2][2]=0.f; acc[rt][c2][3]=0.f; }

        #pragma unroll
        for (int rt = 0; rt < 3; ++rt) {
            int r = rt * 16 + col;
            short8 af[4];
            #pragma unroll
            for (int ks = 0; ks < 4; ++ks) af[ks] = *(const short8*)&Al[swz(r, ks * 4 + kg) * 8];
            #pragma unroll
            for (int ks = 0; ks < 4; ++ks)
                #pragma unroll
                for (int c2 = 0; c2 < 2; ++c2)
                    acc[rt][c2] = __builtin_amdgcn_mfma_f32_16x16x32_bf16(af[ks], bfr[c2][ks], acc[rt][c2], 0, 0, 0);
        }
        __syncthreads();                             // S2

        // acc -> Hs[(p*3+v)][e] bf16 (final h layout for this 16-pair tile)
        #pragma unroll
        for (int rt = 0; rt < 3; ++rt)
            #pragma unroll
            for (int c2 = 0; c2 < 2; ++c2) {
                int e = (w * 2 + c2) * 16 + col;
                #pragma unroll
                for (int reg = 0; reg < 4; ++reg) {
                    int R = rt * 16 + kg * 4 + reg;
                    Hs[R * 128 + e] = f2bf(acc[rt][c2][reg]);
                }
            }
        __syncthreads();                             // S3

        // coalesced burst: 768 short8 chunks = 12 KB contiguous
        unsigned short* hb = h + (size_t)g0 * 3 * 128;
        #pragma unroll
        for (int t2 = 0; t2 < 3; ++t2) {
            int c = tid + t2 * 256;
            *(short8*)(hb + c * 8) = *(const short8*)&Hs[c * 8];
        }
        __syncthreads();                             // protect Hs/Al for next iter
    }
}

// ---------------- K3: out[b,a,d,v] = sum_e W_out[d][e] * mod[a][e] * h[b,idx[a],v,e]
// 2048 blocks (16 b x 128 a-groups) x 4 sub-tiles of 16 atoms. W_out staged once.
__global__ __launch_bounds__(256) void k_out(const unsigned short* __restrict__ h,
                                             const float* __restrict__ mod,
                                             const int* __restrict__ idx,
                                             const unsigned short* __restrict__ woutB,
                                             float* __restrict__ out) {
    __shared__ short Al[48 * 128];
    __shared__ short Bl[128 * 128];
    float* Os = (float*)Bl;                          // epilogue staging aliases Bl (24 KB <= 32 KB)
    const int tid = threadIdx.x;
    const int b = blockIdx.x & 15;
    const int abase = (blockIdx.x >> 4) * 64;

    #pragma unroll
    for (int t = 0; t < 8; ++t) {
        int cc = tid + t * 256;
        int rr = cc >> 4, ch = cc & 15;
        short8 v = *(const short8*)(woutB + cc * 8);
        *(short8*)&Bl[swz(rr, ch) * 8] = v;
    }
    __syncthreads();

    const int lane = tid & 63, w = tid >> 6;
    const int col = lane & 15, kg = lane >> 4;

    short8 bfr[2][4];                                // hoisted W_out fragments
    #pragma unroll
    for (int c2 = 0; c2 < 2; ++c2) {
        int r = (w * 2 + c2) * 16 + col;
        #pragma unroll
        for (int ks = 0; ks < 4; ++ks) bfr[c2][ks] = *(const short8*)&Bl[swz(r, ks * 4 + kg) * 8];
    }

    for (int it = 0; it < 4; ++it) {
        const int a0 = abase + it * 16;
        // stage A: gather h rows and modulate
        #pragma unroll
        for (int t = 0; t < 3; ++t) {
            int task = tid + t * 256;                // 768 tasks: 48 rows x 16 chunks
            int row = task >> 4, ch = task & 15;
            int al = row / 3, v = row - 3 * al;
            int a = a0 + al;
            int ia = idx[a];
            short8 hv = *(const short8*)(h + (size_t)((b * AMINOS + ia) * 3 + v) * 128 + ch * 8);
            const f32x4* mp = (const f32x4*)(mod + a * 128 + ch * 8);
            f32x4 m0 = mp[0], m1 = mp[1];
            short8 vv;
            vv[0]=(short)f2bf(bf2f((unsigned short)hv[0]) * m0[0]);
            vv[1]=(short)f2bf(bf2f((unsigned short)hv[1]) * m0[1]);
            vv[2]=(short)f2bf(bf2f((unsigned short)hv[2]) * m0[2]);
            vv[3]=(short)f2bf(bf2f((unsigned short)hv[3]) * m0[3]);
            vv[4]=(short)f2bf(bf2f((unsigned short)hv[4]) * m1[0]);
            vv[5]=(short)f2bf(bf2f((unsigned short)hv[5]) * m1[1]);
            vv[6]=(short)f2bf(bf2f((unsigned short)hv[6]) * m1[2]);
            vv[7]=(short)f2bf(bf2f((unsigned short)hv[7]) * m1[3]);
            *(short8*)&Al[swz(row, ch) * 8] = vv;
        }
        __syncthreads();                             // S1

        f32x4 acc[3][2];
        #pragma unroll
        for (int rt = 0; rt < 3; ++rt)
            #pragma unroll
            for (int c2 = 0; c2 < 2; ++c2) { acc[rt][c2][0]=0.f; acc[rt][c2][1]=0.f; acc[rt][c2][2]=0.f; acc[rt][c2][3]=0.f; }

        #pragma unroll
        for (int rt = 0; rt < 3; ++rt) {
            int r = rt * 16 + col;
            short8 af[4];
            #pragma unroll
            for (int ks = 0; ks < 4; ++ks) af[ks] = *(const short8*)&Al[swz(r, ks * 4 + kg) * 8];
            #pragma unroll
            for (int ks = 0; ks < 4; ++ks)
                #pragma unroll
                for (int c2 = 0; c2 < 2; ++c2)
                    acc[rt][c2] = __builtin_amdgcn_mfma_f32_16x16x32_bf16(af[ks], bfr[c2][ks], acc[rt][c2], 0, 0, 0);
        }
        __syncthreads();                             // S2

        // acc -> Os[al*384 + d*3 + v] f32 (final out layout for this 16-atom tile)
        #pragma unroll
        for (int rt = 0; rt < 3; ++rt)
            #pragma unroll
            for (int c2 = 0; c2 < 2; ++c2) {
                int d = (w * 2 + c2) * 16 + col;
                #pragma unroll
                for (int reg = 0; reg < 4; ++reg) {
                    int R = rt * 16 + kg * 4 + reg;
                    int al = R / 3, v = R - 3 * al;
                    Os[al * 384 + d * 3 + v] = acc[rt][c2][reg];
                }
            }
        __syncthreads();                             // S3

        // coalesced burst: 1536 f32x4 chunks = 24 KB contiguous
        float* ob = out + ((size_t)b * ATOMS + a0) * 384;
        #pragma unroll
        for (int t2 = 0; t2 < 6; ++t2) {
            int c = tid + t2 * 256;
            *(f32x4*)(ob + c * 4) = *(const f32x4*)&Os[c * 4];
        }
        __syncthreads();                             // protect Os/Al for next iter
    }
}

extern "C" void kernel_launch(void* const* d_in, const int* in_sizes, int n_in,
                              void* d_out, int out_size, void* d_ws, size_t ws_size,
                              hipStream_t stream) {
    const float* x    = (const float*)d_in[0];
    const float* emb  = (const float*)d_in[1];
    const int*   idx  = (const int*)d_in[2];
    const float* wemb = (const float*)d_in[3];
    const float* bemb = (const float*)d_in[4];
    const float* win  = (const float*)d_in[5];
    const float* wout = (const float*)d_in[6];
    float* out = (float*)d_out;

    char* ws = (char*)d_ws;
    float*          mod = (float*)ws;                              // 8192*128 f32   = 4 MiB
    unsigned short* h   = (unsigned short*)(ws + (4u << 20));      // 16*1024*3*128 bf16 = 12 MiB
    unsigned short* wB  = (unsigned short*)(ws + 16777216u);       // 3 x 16384 bf16

    k_convert<<<192, 256, 0, stream>>>(wemb, win, wout, wB);
    k_mod    <<<128, 256, 0, stream>>>(emb, wB, bemb, mod);
    k_h      <<<256, 256, 0, stream>>>(x, wB + 16384, h);
    k_out    <<<2048, 256, 0, stream>>>(h, mod, idx, wB + 32768, out);
}

// Round 5
// 245.310 us; speedup vs baseline: 1.0727x; 1.0004x over previous
//
#include <hip/hip_runtime.h>
#include <hip/hip_bf16.h>

#define AMINOS 1024
#define ATOMS  8192

typedef __attribute__((ext_vector_type(8))) short  short8;   // 8 bf16 (4 VGPRs)
typedef __attribute__((ext_vector_type(4))) float  f32x4;

// RNE float -> bf16 (finite inputs only)
__device__ __forceinline__ unsigned short f2bf(float f) {
    unsigned int u; __builtin_memcpy(&u, &f, 4);
    unsigned int r = (u + 0x7fffu + ((u >> 16) & 1u)) >> 16;
    return (unsigned short)r;
}
__device__ __forceinline__ float bf2f(unsigned short us) {
    unsigned int x = ((unsigned int)us) << 16;
    float f; __builtin_memcpy(&f, &x, 4);
    return f;
}

// 16-byte-slot index with XOR swizzle inside a [rows][16-slot] LDS tile
__device__ __forceinline__ int swz(int row, int ch) { return row * 16 + (ch ^ (row & 7)); }

// Stage a 128x128 f32 weight matrix into a swizzled bf16 LDS tile (needs 32 KB at Bl)
__device__ __forceinline__ void stage_w_f32(const float* __restrict__ W, short* Bl, int tid) {
    #pragma unroll
    for (int t = 0; t < 8; ++t) {
        int cc = tid + t * 256;                      // 2048 chunks of 8 elements
        int rr = cc >> 4, ch = cc & 15;
        const f32x4* p = (const f32x4*)(W + cc * 8);
        f32x4 lo = p[0], hi = p[1];
        short8 v;
        v[0]=(short)f2bf(lo[0]); v[1]=(short)f2bf(lo[1]); v[2]=(short)f2bf(lo[2]); v[3]=(short)f2bf(lo[3]);
        v[4]=(short)f2bf(hi[0]); v[5]=(short)f2bf(hi[1]); v[6]=(short)f2bf(hi[2]); v[7]=(short)f2bf(hi[3]);
        *(short8*)&Bl[swz(rr, ch) * 8] = v;
    }
}

// ---------------- K_pre: blocks [0,128) -> mod ; blocks [128,384) -> h ----------------
// mod[a][f] = sum_e emb[a][e]*W_emb[f][e] + b_emb[f]            (f32 out)
// h[g][v][e] = sum_c x[g][c][v]*W_in[e][c]                      (bf16 out)
__global__ __launch_bounds__(256) void k_pre(const float* __restrict__ emb,
                                             const float* __restrict__ wemb,
                                             const float* __restrict__ bemb,
                                             const float* __restrict__ x,
                                             const float* __restrict__ win,
                                             float* __restrict__ mod,
                                             unsigned short* __restrict__ h) {
    __shared__ short Al[64 * 128];                   // 16 KB
    __shared__ short Bl[128 * 128];                  // 32 KB
    const int tid = threadIdx.x;
    const int lane = tid & 63, w = tid >> 6;
    const int col = lane & 15, kg = lane >> 4;

    if (blockIdx.x < 128) {
        // ================= MOD =================
        const int a0 = blockIdx.x * 64;
        #pragma unroll
        for (int t = 0; t < 4; ++t) {
            int task = tid + t * 256;                // 1024 tasks: 64 rows x 16 chunks
            int row = task >> 4, ch = task & 15;
            const f32x4* p = (const f32x4*)(emb + (row + a0) * 128 + ch * 8);
            f32x4 lo = p[0], hi = p[1];
            short8 v;
            v[0]=(short)f2bf(lo[0]); v[1]=(short)f2bf(lo[1]); v[2]=(short)f2bf(lo[2]); v[3]=(short)f2bf(lo[3]);
            v[4]=(short)f2bf(hi[0]); v[5]=(short)f2bf(hi[1]); v[6]=(short)f2bf(hi[2]); v[7]=(short)f2bf(hi[3]);
            *(short8*)&Al[swz(row, ch) * 8] = v;
        }
        stage_w_f32(wemb, Bl, tid);
        __syncthreads();

        const int rt = w;
        short8 af[4];
        #pragma unroll
        for (int ks = 0; ks < 4; ++ks) af[ks] = *(const short8*)&Al[swz(rt * 16 + col, ks * 4 + kg) * 8];

        f32x4 acc[8];
        #pragma unroll
        for (int ct = 0; ct < 8; ++ct) { acc[ct][0]=0.f; acc[ct][1]=0.f; acc[ct][2]=0.f; acc[ct][3]=0.f; }

        #pragma unroll
        for (int ct = 0; ct < 8; ++ct) {
            int r = ct * 16 + col;
            #pragma unroll
            for (int ks = 0; ks < 4; ++ks) {
                short8 bf = *(const short8*)&Bl[swz(r, ks * 4 + kg) * 8];
                acc[ct] = __builtin_amdgcn_mfma_f32_16x16x32_bf16(af[ks], bf, acc[ct], 0, 0, 0);
            }
        }
        #pragma unroll
        for (int ct = 0; ct < 8; ++ct) {
            int f = ct * 16 + col;
            float bb = bemb[f];
            #pragma unroll
            for (int reg = 0; reg < 4; ++reg) {
                int r = rt * 16 + kg * 4 + reg;
                mod[(a0 + r) * 128 + f] = acc[ct][reg] + bb;
            }
        }
    } else {
        // ================= H =================
        unsigned short* Hs = (unsigned short*)Bl;    // epilogue staging aliases Bl
        stage_w_f32(win, Bl, tid);
        __syncthreads();

        short8 bfr[2][4];                            // hoisted W_in fragments
        #pragma unroll
        for (int c2 = 0; c2 < 2; ++c2) {
            int r = (w * 2 + c2) * 16 + col;
            #pragma unroll
            for (int ks = 0; ks < 4; ++ks) bfr[c2][ks] = *(const short8*)&Bl[swz(r, ks * 4 + kg) * 8];
        }

        for (int it = 0; it < 4; ++it) {
            const int g0 = (blockIdx.x - 128) * 64 + it * 16;
            {
                int p = tid >> 4, ch = tid & 15;
                const f32x4* q = (const f32x4*)(x + (size_t)(g0 + p) * 384 + ch * 24);
                f32x4 q0 = q[0], q1 = q[1], q2 = q[2], q3 = q[3], q4 = q[4], q5 = q[5];
                float e[24];
                *(f32x4*)&e[0]  = q0; *(f32x4*)&e[4]  = q1; *(f32x4*)&e[8]  = q2;
                *(f32x4*)&e[12] = q3; *(f32x4*)&e[16] = q4; *(f32x4*)&e[20] = q5;
                #pragma unroll
                for (int v = 0; v < 3; ++v) {
                    short8 vv;
                    #pragma unroll
                    for (int i = 0; i < 8; ++i) vv[i] = (short)f2bf(e[v + 3 * i]);
                    *(short8*)&Al[swz(p * 3 + v, ch) * 8] = vv;
                }
            }
            __syncthreads();                         // S1

            f32x4 acc[3][2];
            #pragma unroll
            for (int rt = 0; rt < 3; ++rt)
                #pragma unroll
                for (int c2 = 0; c2 < 2; ++c2) { acc[rt][c2][0]=0.f; acc[rt][c2][1]=0.f; acc[rt][c2][2]=0.f; acc[rt][c2][3]=0.f; }

            #pragma unroll
            for (int rt = 0; rt < 3; ++rt) {
                int r = rt * 16 + col;
                short8 af[4];
                #pragma unroll
                for (int ks = 0; ks < 4; ++ks) af[ks] = *(const short8*)&Al[swz(r, ks * 4 + kg) * 8];
                #pragma unroll
                for (int ks = 0; ks < 4; ++ks)
                    #pragma unroll
                    for (int c2 = 0; c2 < 2; ++c2)
                        acc[rt][c2] = __builtin_amdgcn_mfma_f32_16x16x32_bf16(af[ks], bfr[c2][ks], acc[rt][c2], 0, 0, 0);
            }
            __syncthreads();                         // S2

            #pragma unroll
            for (int rt = 0; rt < 3; ++rt)
                #pragma unroll
                for (int c2 = 0; c2 < 2; ++c2) {
                    int e = (w * 2 + c2) * 16 + col;
                    #pragma unroll
                    for (int reg = 0; reg < 4; ++reg) {
                        int R = rt * 16 + kg * 4 + reg;
                        Hs[R * 128 + e] = f2bf(acc[rt][c2][reg]);
                    }
                }
            __syncthreads();                         // S3

            unsigned short* hb = h + (size_t)g0 * 3 * 128;
            #pragma unroll
            for (int t2 = 0; t2 < 3; ++t2) {
                int c = tid + t2 * 256;
                *(short8*)(hb + c * 8) = *(const short8*)&Hs[c * 8];
            }
            __syncthreads();                         // protect Hs/Al for next iter
        }
    }
}

// ---------------- K_out: out[b,a,d,v] = sum_e W_out[d][e] * mod[a][e] * h[b,idx[a],v,e]
// 2048 blocks (16 b x 128 a-groups) x 4 sub-tiles of 16 atoms. 36 KB LDS -> 4 blocks/CU.
__global__ __launch_bounds__(256) void k_out(const unsigned short* __restrict__ h,
                                             const float* __restrict__ mod,
                                             const int* __restrict__ idx,
                                             const float* __restrict__ wout,
                                             float* __restrict__ out) {
    __shared__ short L[18432];                       // 36 KB total
    const int tid = threadIdx.x;
    const int b = blockIdx.x & 15;
    const int abase = (blockIdx.x >> 4) * 64;
    const int lane = tid & 63, w = tid >> 6;
    const int col = lane & 15, kg = lane >> 4;

    // one-time: stage W_out (f32 -> swizzled bf16) into L[0..16384), hoist frags, then free it
    stage_w_f32(wout, L, tid);
    __syncthreads();
    short8 bfr[2][4];
    #pragma unroll
    for (int c2 = 0; c2 < 2; ++c2) {
        int r = (w * 2 + c2) * 16 + col;
        #pragma unroll
        for (int ks = 0; ks < 4; ++ks) bfr[c2][ks] = *(const short8*)&L[swz(r, ks * 4 + kg) * 8];
    }
    __syncthreads();                                 // W region now dead

    short* Al = L;                                   // 12 KB: A tile
    float* Os = (float*)(L + 6144);                  // 24 KB: epilogue staging

    for (int it = 0; it < 4; ++it) {
        const int a0 = abase + it * 16;
        #pragma unroll
        for (int t = 0; t < 3; ++t) {
            int task = tid + t * 256;                // 768 tasks: 48 rows x 16 chunks
            int row = task >> 4, ch = task & 15;
            int al = row / 3, v = row - 3 * al;
            int a = a0 + al;
            int ia = idx[a];
            short8 hv = *(const short8*)(h + (size_t)((b * AMINOS + ia) * 3 + v) * 128 + ch * 8);
            const f32x4* mp = (const f32x4*)(mod + a * 128 + ch * 8);
            f32x4 m0 = mp[0], m1 = mp[1];
            short8 vv;
            vv[0]=(short)f2bf(bf2f((unsigned short)hv[0]) * m0[0]);
            vv[1]=(short)f2bf(bf2f((unsigned short)hv[1]) * m0[1]);
            vv[2]=(short)f2bf(bf2f((unsigned short)hv[2]) * m0[2]);
            vv[3]=(short)f2bf(bf2f((unsigned short)hv[3]) * m0[3]);
            vv[4]=(short)f2bf(bf2f((unsigned short)hv[4]) * m1[0]);
            vv[5]=(short)f2bf(bf2f((unsigned short)hv[5]) * m1[1]);
            vv[6]=(short)f2bf(bf2f((unsigned short)hv[6]) * m1[2]);
            vv[7]=(short)f2bf(bf2f((unsigned short)hv[7]) * m1[3]);
            *(short8*)&Al[swz(row, ch) * 8] = vv;
        }
        __syncthreads();                             // S1

        f32x4 acc[3][2];
        #pragma unroll
        for (int rt = 0; rt < 3; ++rt)
            #pragma unroll
            for (int c2 = 0; c2 < 2; ++c2) { acc[rt][c2][0]=0.f; acc[rt][c2][1]=0.f; acc[rt][c2][2]=0.f; acc[rt][c2][3]=0.f; }

        #pragma unroll
        for (int rt = 0; rt < 3; ++rt) {
            int r = rt * 16 + col;
            short8 af[4];
            #pragma unroll
            for (int ks = 0; ks < 4; ++ks) af[ks] = *(const short8*)&Al[swz(r, ks * 4 + kg) * 8];
            #pragma unroll
            for (int ks = 0; ks < 4; ++ks)
                #pragma unroll
                for (int c2 = 0; c2 < 2; ++c2)
                    acc[rt][c2] = __builtin_amdgcn_mfma_f32_16x16x32_bf16(af[ks], bfr[c2][ks], acc[rt][c2], 0, 0, 0);
        }
        __syncthreads();                             // S2

        #pragma unroll
        for (int rt = 0; rt < 3; ++rt)
            #pragma unroll
            for (int c2 = 0; c2 < 2; ++c2) {
                int d = (w * 2 + c2) * 16 + col;
                #pragma unroll
                for (int reg = 0; reg < 4; ++reg) {
                    int R = rt * 16 + kg * 4 + reg;
                    int al = R / 3, v = R - 3 * al;
                    Os[al * 384 + d * 3 + v] = acc[rt][c2][reg];
                }
            }
        __syncthreads();                             // S3

        float* ob = out + ((size_t)b * ATOMS + a0) * 384;
        #pragma unroll
        for (int t2 = 0; t2 < 6; ++t2) {
            int c = tid + t2 * 256;
            f32x4 vv = *(const f32x4*)&Os[c * 4];
            __builtin_nontemporal_store(vv, (f32x4*)(ob + c * 4));
        }
        __syncthreads();                             // protect Os/Al for next iter
    }
}

extern "C" void kernel_launch(void* const* d_in, const int* in_sizes, int n_in,
                              void* d_out, int out_size, void* d_ws, size_t ws_size,
                              hipStream_t stream) {
    const float* x    = (const float*)d_in[0];
    const float* emb  = (const float*)d_in[1];
    const int*   idx  = (const int*)d_in[2];
    const float* wemb = (const float*)d_in[3];
    const float* bemb = (const float*)d_in[4];
    const float* win  = (const float*)d_in[5];
    const float* wout = (const float*)d_in[6];
    float* out = (float*)d_out;

    char* ws = (char*)d_ws;
    float*          mod = (float*)ws;                              // 8192*128 f32   = 4 MiB
    unsigned short* h   = (unsigned short*)(ws + (4u << 20));      // 16*1024*3*128 bf16 = 12 MiB

    k_pre<<<384, 256, 0, stream>>>(emb, wemb, bemb, x, win, mod, h);
    k_out<<<2048, 256, 0, stream>>>(h, mod, idx, wout, out);
}